// Round 9
// baseline (3709.865 us; speedup 1.0000x reference)
//
#include <hip/hip_runtime.h>
#include <hip/hip_cooperative_groups.h>

namespace cg = cooperative_groups;

// ---------------- problem constants (match reference) ----------------
#define Zl      384
#define MBr     46
#define NBc     68
#define DEG     7
#define K_INFO  8448
#define N_TX    25344
#define N_LDPC  (NBc * Zl)        // 26112
#define M_CHK   (MBr * Zl)        // 17664
#define E_EDGE  (MBr * DEG * Zl)  // 123648
#define BATCH   128
#define NUM_ITER 20
#define LLR_MAXF 20.0f
#define BCAP    32

#define NBLK    512
#define NTHR    256

// NUMERICS CONTRACT (validated rounds 7-8, absmax 0.0625 vs 0.45):
//  - pure f32 end to end
//  - VN sum: accumulator starts at lch[v], then messages added in
//    ASCENDING edge-id order (XLA scatter-fusion order). Changing this
//    order produces absmax ~1.4-2.0 (measured R1-R6). DO NOT REORDER.
//  - CN: two-min with strict < (first-argmin), sign via parity mask.
// Batch elements are independent -> float4 over batch is order-safe.

__global__ __launch_bounds__(NTHR, 2) void persist_kernel(
    const float* __restrict__ llr, const int* __restrict__ col,
    float* __restrict__ out, float* __restrict__ lch, float* __restrict__ x,
    float* __restrict__ mcv, int* __restrict__ bcount, int* __restrict__ badj)
{
    cg::grid_group grid = cg::this_grid();
    const int tid = threadIdx.x;
    const int bid = blockIdx.x;
    const int nb  = gridDim.x;

    __shared__ float tile[32][33];
    __shared__ int sc[MBr * DEG];
    __shared__ int ssh[MBr * DEG];

    const int tx = tid & 31, ty = tid >> 5;

    // ================= phase 0: zero lch head + build + prep =================
    for (int idx = bid * NTHR + tid; idx < 2 * Zl * BATCH; idx += nb * NTHR)
        lch[idx] = 0.f;

    if (bid == 0) {
        // deterministic adjacency: slot = rank among same-column base edges
        for (int t = tid; t < MBr * DEG; t += NTHR) {
            const int v0 = col[t * Zl];       // col[be*Z] = c*Z + shift
            const int c  = v0 / Zl;
            sc[t]  = c;
            ssh[t] = v0 - c * Zl;
        }
        for (int t = tid; t < NBc; t += NTHR) bcount[t] = 0;
        __syncthreads();
        for (int t = tid; t < MBr * DEG; t += NTHR) {
            const int c = sc[t];
            int slot = 0;
            for (int u = 0; u < t; ++u) slot += (sc[u] == c) ? 1 : 0;
            if (slot < BCAP) badj[c * BCAP + slot] = (t << 16) | ssh[t];
            atomicAdd(&bcount[c], 1);     // order-independent (count only)
        }
    }

    // prep: lch[(2Z+n)*128+b] = -clip(llr[b*N_TX+n]), 32x32 transpose tiles
    for (int tt = bid; tt < (N_TX / 32) * (BATCH / 32); tt += nb) {
        const int n0 = (tt % (N_TX / 32)) * 32;
        const int b0 = (tt / (N_TX / 32)) * 32;
        __syncthreads();                 // tile[] reuse across loop trips
#pragma unroll
        for (int j = 0; j < 4; ++j) {
            float v = llr[(b0 + ty + 8 * j) * N_TX + n0 + tx];
            v = fminf(fmaxf(v, -LLR_MAXF), LLR_MAXF);
            tile[ty + 8 * j][tx] = -v;   // [b_local][n_local]
        }
        __syncthreads();
#pragma unroll
        for (int j = 0; j < 4; ++j)
            lch[(2 * Zl + n0 + ty + 8 * j) * BATCH + b0 + tx] = tile[tx][ty + 8 * j];
    }

    grid.sync();

    // ========================= iteration loop =========================
    for (int it = 0; it < NUM_ITER; ++it) {
        const bool first = (it == 0);
        const float* __restrict__ xs = first ? lch : x;

        // ---- CN phase: tile = 8 check nodes, 32 lanes (float4) each ----
        for (int ti = bid; ti < M_CHK / 8; ti += nb) {
            const int q   = tid & 31;
            const int sub = tid >> 5;
            const int cn  = ti * 8 + sub;
            const int r   = cn / Zl;
            const int i   = cn - r * Zl;
            const int ebase = r * DEG * Zl + i;

            float min1[4] = {1e30f, 1e30f, 1e30f, 1e30f};
            float min2[4] = {1e30f, 1e30f, 1e30f, 1e30f};
            int   amin[4] = {0, 0, 0, 0};
            unsigned nm[4] = {0u, 0u, 0u, 0u};

#pragma unroll
            for (int d = 0; d < DEG; ++d) {
                const int e = ebase + d * Zl;
                const int v = col[e];
                const float4 xv = ((const float4*)xs)[v * 32 + q];
                float4 mc = make_float4(0.f, 0.f, 0.f, 0.f);
                if (!first) mc = ((const float4*)mcv)[e * 32 + q];
                const float t[4] = {xv.x - mc.x, xv.y - mc.y, xv.z - mc.z, xv.w - mc.w};
#pragma unroll
                for (int c = 0; c < 4; ++c) {
                    const float mag = fabsf(t[c]);
                    nm[c] |= (t[c] < 0.f ? 1u : 0u) << d;
                    if (mag < min1[c]) { min2[c] = min1[c]; min1[c] = mag; amin[c] = d; }
                    else if (mag < min2[c]) { min2[c] = mag; }
                }
            }

            float stot[4];
#pragma unroll
            for (int c = 0; c < 4; ++c) stot[c] = (__popc(nm[c]) & 1) ? -1.f : 1.f;

#pragma unroll
            for (int d = 0; d < DEG; ++d) {
                const int e = ebase + d * Zl;
                float o[4];
#pragma unroll
                for (int c = 0; c < 4; ++c) {
                    const float m = (d == amin[c]) ? min2[c] : min1[c];
                    const float s = ((nm[c] >> d) & 1u) ? -stot[c] : stot[c];
                    o[c] = s * m;
                }
                ((float4*)mcv)[e * 32 + q] = make_float4(o[0], o[1], o[2], o[3]);
            }
        }

        grid.sync();

        // ---- VN phase (LCH-FIRST, ascending edge id) ----
        for (int ti = bid; ti < N_LDPC / 8; ti += nb) {
            const int q   = tid & 31;
            const int sub = tid >> 5;
            const int v   = ti * 8 + sub;
            const int c   = v / Zl;
            const int j   = v - c * Zl;
            const int cnt = min(bcount[c], BCAP);
            const int* bp = badj + c * BCAP;
            float4 s = ((const float4*)lch)[v * 32 + q];   // lch FIRST
            for (int k = 0; k < cnt; ++k) {
                const int pk = bp[k];
                const int be = pk >> 16;
                const int sh = pk & 0xFFFF;
                int i = j - sh;
                if (i < 0) i += Zl;
                const float4 m = ((const float4*)mcv)[(be * Zl + i) * 32 + q];
                s.x += m.x; s.y += m.y; s.z += m.z; s.w += m.w;
            }
            ((float4*)x)[v * 32 + q] = s;
        }

        grid.sync();
    }

    // ================= out: out[b*K+k] = -x[k*128+b] =================
    for (int tt = bid; tt < (K_INFO / 32) * (BATCH / 32); tt += nb) {
        const int k0 = (tt % (K_INFO / 32)) * 32;
        const int b0 = (tt / (K_INFO / 32)) * 32;
        __syncthreads();
#pragma unroll
        for (int j = 0; j < 4; ++j)
            tile[ty + 8 * j][tx] = -x[(k0 + ty + 8 * j) * BATCH + b0 + tx];
        __syncthreads();
#pragma unroll
        for (int j = 0; j < 4; ++j)
            out[(b0 + ty + 8 * j) * K_INFO + k0 + tx] = tile[tx][ty + 8 * j];
    }
}

// ---------------------------------------------------------------------
extern "C" void kernel_launch(void* const* d_in, const int* in_sizes, int n_in,
                              void* d_out, int out_size, void* d_ws, size_t ws_size,
                              hipStream_t stream) {
    const float* llr = (const float*)d_in[0];
    // d_in[1] = row (unused: row index derivable from edge-id structure)
    const int* col = (const int*)d_in[2];
    float* out = (float*)d_out;

    char* ws = (char*)d_ws;
    float* lch    = (float*)ws;                                  // 13,369,344 B
    float* x      = lch + (size_t)N_LDPC * BATCH;                // 13,369,344 B
    float* mcv    = x + (size_t)N_LDPC * BATCH;                  // 63,307,776 B
    int*   bcount = (int*)(mcv + (size_t)E_EDGE * BATCH);        // 68*4
    int*   badj   = bcount + NBc;                                // 68*32*4

    void* args[] = {(void*)&llr, (void*)&col, (void*)&out, (void*)&lch,
                    (void*)&x, (void*)&mcv, (void*)&bcount, (void*)&badj};
    hipLaunchCooperativeKernel((void*)persist_kernel, dim3(NBLK), dim3(NTHR),
                               args, 0, stream);
}

// Round 10
// 925.625 us; speedup vs baseline: 4.0080x; 4.0080x over previous
//
#include <hip/hip_runtime.h>

// ---------------- problem constants (match reference) ----------------
#define Zl      384
#define MBr     46
#define NBc     68
#define DEG     7
#define K_INFO  8448
#define N_TX    25344
#define N_LDPC  (NBc * Zl)        // 26112
#define M_CHK   (MBr * Zl)        // 17664
#define E_EDGE  (MBr * DEG * Zl)  // 123648
#define BATCH   128
#define NUM_ITER 20
#define LLR_MAXF 20.0f
#define BCAP    32

// NUMERICS CONTRACT (validated rounds 7-9, absmax 0.0625 vs 0.45):
//  - pure f32 end to end
//  - VN sum: accumulator starts at lch[v], then messages added in
//    ASCENDING edge-id order. DO NOT REORDER (other orders: 1.4-2.0).
//  - CN: two-min with strict < (first-argmin), sign via parity mask.
//  - CN state compression is EXACT: messages are +-min1/+-min2, and the
//    reconstruction flips the sign bit of the identical f32 value.
// Batch elements are independent -> float4 over batch is order-safe.
//
// PERF MODEL (measured R9): L2/L3 absorb gather amplification; Infinity
// Cache does NOT retain across phases -> HBM traffic == unique bytes per
// phase. So minimize unique state bytes: (min1,min2,meta) = 10B/cn/b
// instead of 7 f32 messages = 28B/cn/b.

// meta bits: [2:0]=amin, [9:3]=nm (neg mask), [10]=stot (parity)

// ---------------------------------------------------------------------
// prep: lch[(2Z+n)*128 + b] = -clip(llr[b*N_TX + n])   (tiled transpose)
// ---------------------------------------------------------------------
__global__ void prep_kernel(const float* __restrict__ llr, float* __restrict__ lch) {
    __shared__ float tile[32][33];
    const int n0 = blockIdx.x * 32, b0 = blockIdx.y * 32;
    const int tx = threadIdx.x, ty = threadIdx.y;
#pragma unroll
    for (int j = 0; j < 4; ++j) {
        float v = llr[(b0 + ty + 8 * j) * N_TX + n0 + tx];
        v = fminf(fmaxf(v, -LLR_MAXF), LLR_MAXF);
        tile[ty + 8 * j][tx] = -v;          // [b_local][n_local]
    }
    __syncthreads();
#pragma unroll
    for (int j = 0; j < 4; ++j) {
        lch[(2 * Zl + n0 + ty + 8 * j) * BATCH + b0 + tx] = tile[tx][ty + 8 * j];
    }
}

// ---------------------------------------------------------------------
// adjacency build, deterministic ascending base-edge order.
// badj[c*BCAP + slot] = sh | (d<<10) | (r<<13)   (sh<512, d<8, r<64)
// ---------------------------------------------------------------------
__global__ void base_build_kernel(const int* __restrict__ col,
                                  int* __restrict__ bcount, int* __restrict__ badj) {
    __shared__ int sc[MBr * DEG];
    __shared__ int ssh[MBr * DEG];
    const int t = threadIdx.x;
    if (t < MBr * DEG) {
        const int v0 = col[t * Zl];         // col[be*Z] = c*Z + shift
        const int c  = v0 / Zl;
        sc[t]  = c;
        ssh[t] = v0 - c * Zl;
    }
    if (t < NBc) bcount[t] = 0;
    __syncthreads();
    if (t < MBr * DEG) {
        const int c = sc[t];
        int slot = 0;
        for (int u = 0; u < t; ++u) slot += (sc[u] == c) ? 1 : 0;
        const int r = t / DEG, d = t - r * DEG;
        if (slot < BCAP) badj[c * BCAP + slot] = ssh[t] | (d << 10) | (r << 13);
        atomicAdd(&bcount[c], 1);           // order-independent (count only)
    }
}

// ---------------------------------------------------------------------
// CN update: node cn = r*Z + i, edges e_d = (r*DEG+d)*Z + i.
// Reads x (gather) + old compressed state; writes new compressed state.
// 32 lanes per node (4 batch elems each), 8 nodes per 256-thread block.
// state_f2: float2(min1,min2) per (cn,b)  -> float4 loads cover 2 b's.
// meta:     u16 per (cn,b)                -> ushort4 loads cover 4 b's.
// ---------------------------------------------------------------------
template <bool FIRST>
__global__ void cn_kernel(const float* __restrict__ x,
                          float* __restrict__ state_f2,
                          unsigned short* __restrict__ meta,
                          const int* __restrict__ col) {
    const int q   = threadIdx.x & 31;   // covers batch 4q..4q+3
    const int sub = threadIdx.x >> 5;
    const int cn  = blockIdx.x * 8 + sub;
    const int r   = cn / Zl;
    const int i   = cn - r * Zl;
    const int ebase = r * DEG * Zl + i;

    float omin1[4], omin2[4];
    int oamin[4]; unsigned onm[4], ostot[4];
    if (!FIRST) {
        const float4 sA = ((const float4*)state_f2)[cn * 64 + 2 * q];
        const float4 sB = ((const float4*)state_f2)[cn * 64 + 2 * q + 1];
        omin1[0] = sA.x; omin2[0] = sA.y; omin1[1] = sA.z; omin2[1] = sA.w;
        omin1[2] = sB.x; omin2[2] = sB.y; omin1[3] = sB.z; omin2[3] = sB.w;
        const ushort4 mt = ((const ushort4*)meta)[cn * 32 + q];
        const unsigned m4[4] = {mt.x, mt.y, mt.z, mt.w};
#pragma unroll
        for (int c = 0; c < 4; ++c) {
            oamin[c] = m4[c] & 7u;
            onm[c]   = (m4[c] >> 3) & 0x7Fu;
            ostot[c] = (m4[c] >> 10) & 1u;
        }
    }

    float min1[4] = {1e30f, 1e30f, 1e30f, 1e30f};
    float min2[4] = {1e30f, 1e30f, 1e30f, 1e30f};
    int   amin[4] = {0, 0, 0, 0};
    unsigned nm[4] = {0u, 0u, 0u, 0u};

#pragma unroll
    for (int d = 0; d < DEG; ++d) {
        const int e = ebase + d * Zl;
        const int v = col[e];
        const float4 xv = ((const float4*)x)[v * 32 + q];
        float t[4] = {xv.x, xv.y, xv.z, xv.w};
        if (!FIRST) {
#pragma unroll
            for (int c = 0; c < 4; ++c) {
                const float omag = (d == oamin[c]) ? omin2[c] : omin1[c];
                const float mold = (ostot[c] ^ ((onm[c] >> d) & 1u)) ? -omag : omag;
                t[c] -= mold;
            }
        }
#pragma unroll
        for (int c = 0; c < 4; ++c) {
            const float mag = fabsf(t[c]);
            nm[c] |= (t[c] < 0.f ? 1u : 0u) << d;
            if (mag < min1[c]) { min2[c] = min1[c]; min1[c] = mag; amin[c] = d; }
            else if (mag < min2[c]) { min2[c] = mag; }
        }
    }

    float4 oA, oB;
    oA.x = min1[0]; oA.y = min2[0]; oA.z = min1[1]; oA.w = min2[1];
    oB.x = min1[2]; oB.y = min2[2]; oB.z = min1[3]; oB.w = min2[3];
    ((float4*)state_f2)[cn * 64 + 2 * q]     = oA;
    ((float4*)state_f2)[cn * 64 + 2 * q + 1] = oB;
    ushort4 mo;
    unsigned mv[4];
#pragma unroll
    for (int c = 0; c < 4; ++c)
        mv[c] = (unsigned)amin[c] | (nm[c] << 3) | ((unsigned)(__popc(nm[c]) & 1) << 10);
    mo.x = (unsigned short)mv[0]; mo.y = (unsigned short)mv[1];
    mo.z = (unsigned short)mv[2]; mo.w = (unsigned short)mv[3];
    ((ushort4*)meta)[cn * 32 + q] = mo;
}

// ---------------------------------------------------------------------
// VN update (LCH-FIRST): x[v] = lch[v]; then += reconstructed m_cv[e],
// ascending base-edge id (== ascending lifted edge id).
// ---------------------------------------------------------------------
__global__ void vn_kernel(const float* __restrict__ lch,
                          const float* __restrict__ state_f2,
                          const unsigned short* __restrict__ meta,
                          const int* __restrict__ bcount, const int* __restrict__ badj,
                          float* __restrict__ x) {
    const int q   = threadIdx.x & 31;
    const int sub = threadIdx.x >> 5;
    const int v   = blockIdx.x * 8 + sub;
    const int c   = v / Zl;
    const int j   = v - c * Zl;
    const int cnt = min(bcount[c], BCAP);
    const int* bp = badj + c * BCAP;
    float4 s = ((const float4*)lch)[v * 32 + q];   // lch FIRST (scatter init)
    for (int k = 0; k < cnt; ++k) {
        const int pk = bp[k];
        const int sh = pk & 0x3FF;
        const int d  = (pk >> 10) & 7;
        const int r  = pk >> 13;
        int i = j - sh;
        if (i < 0) i += Zl;
        const int cn = r * Zl + i;
        const float4 sA = ((const float4*)state_f2)[cn * 64 + 2 * q];
        const float4 sB = ((const float4*)state_f2)[cn * 64 + 2 * q + 1];
        const ushort4 mt = ((const ushort4*)meta)[cn * 32 + q];
        const unsigned m4[4] = {mt.x, mt.y, mt.z, mt.w};
        const float mn1[4] = {sA.x, sA.z, sB.x, sB.z};
        const float mn2[4] = {sA.y, sA.w, sB.y, sB.w};
        float val[4];
#pragma unroll
        for (int cc = 0; cc < 4; ++cc) {
            const int   am  = m4[cc] & 7u;
            const unsigned nmv = (m4[cc] >> 3) & 0x7Fu;
            const unsigned st  = (m4[cc] >> 10) & 1u;
            const float mag = (d == am) ? mn2[cc] : mn1[cc];
            val[cc] = (st ^ ((nmv >> d) & 1u)) ? -mag : mag;
        }
        s.x += val[0]; s.y += val[1]; s.z += val[2]; s.w += val[3];
    }
    ((float4*)x)[v * 32 + q] = s;
}

// ---------------------------------------------------------------------
// output: out[b*K + k] = -x[k*128 + b], k < K_INFO   (tiled transpose)
// ---------------------------------------------------------------------
__global__ void out_kernel(const float* __restrict__ x, float* __restrict__ out) {
    __shared__ float tile[32][33];
    const int k0 = blockIdx.x * 32, b0 = blockIdx.y * 32;
    const int tx = threadIdx.x, ty = threadIdx.y;
#pragma unroll
    for (int j = 0; j < 4; ++j) {
        tile[ty + 8 * j][tx] = -x[(k0 + ty + 8 * j) * BATCH + b0 + tx];
    }
    __syncthreads();
#pragma unroll
    for (int j = 0; j < 4; ++j) {
        out[(b0 + ty + 8 * j) * K_INFO + k0 + tx] = tile[tx][ty + 8 * j];
    }
}

// ---------------------------------------------------------------------
extern "C" void kernel_launch(void* const* d_in, const int* in_sizes, int n_in,
                              void* d_out, int out_size, void* d_ws, size_t ws_size,
                              hipStream_t stream) {
    const float* llr = (const float*)d_in[0];
    // d_in[1] = row (unused: row index derivable from edge-id structure)
    const int* col = (const int*)d_in[2];
    float* out = (float*)d_out;

    char* ws = (char*)d_ws;
    float* lch   = (float*)ws;                                   // 13,369,344 B
    float* x     = lch + (size_t)N_LDPC * BATCH;                 // 13,369,344 B
    float* state = x + (size_t)N_LDPC * BATCH;                   // 18,087,936 B
    unsigned short* meta = (unsigned short*)(state + (size_t)M_CHK * BATCH * 2); // 4,521,984 B
    int* bcount = (int*)(meta + (size_t)M_CHK * BATCH);          // 68*4
    int* badj   = bcount + NBc;                                  // 68*32*4
    // total ~49.4 MB

    hipMemsetAsync(lch, 0, (size_t)(2 * Zl) * BATCH * sizeof(float), stream);
    prep_kernel<<<dim3(N_TX / 32, BATCH / 32), dim3(32, 8), 0, stream>>>(llr, lch);

    base_build_kernel<<<1, 512, 0, stream>>>(col, bcount, badj);

    // iteration 1: vn_sum == lch exactly (m_cv == 0)
    cn_kernel<true><<<M_CHK / 8, 256, 0, stream>>>(lch, state, meta, col);
    vn_kernel<<<N_LDPC / 8, 256, 0, stream>>>(lch, state, meta, bcount, badj, x);

    for (int t = 1; t < NUM_ITER; ++t) {
        cn_kernel<false><<<M_CHK / 8, 256, 0, stream>>>(x, state, meta, col);
        vn_kernel<<<N_LDPC / 8, 256, 0, stream>>>(lch, state, meta, bcount, badj, x);
    }

    out_kernel<<<dim3(K_INFO / 32, BATCH / 32), dim3(32, 8), 0, stream>>>(x, out);
}

// Round 11
// 911.592 us; speedup vs baseline: 4.0697x; 1.0154x over previous
//
#include <hip/hip_runtime.h>

// ---------------- problem constants (match reference) ----------------
#define Zl      384
#define MBr     46
#define NBc     68
#define DEG     7
#define K_INFO  8448
#define N_TX    25344
#define N_LDPC  (NBc * Zl)        // 26112
#define M_CHK   (MBr * Zl)        // 17664
#define E_EDGE  (MBr * DEG * Zl)  // 123648
#define BATCH   128
#define NUM_ITER 20
#define LLR_MAXF 20.0f
#define BCAP    32

// NUMERICS CONTRACT (validated rounds 7-10, absmax 0.0625 vs 0.45):
//  - pure f32 end to end
//  - VN sum: accumulator starts at lch[v], then messages added in
//    ASCENDING edge-id order. DO NOT REORDER (other orders: 1.4-2.0).
//  - CN: two-min with strict < (first-argmin), sign via parity mask.
//  - CN state compression is EXACT (messages are +-min1/+-min2).
// Batch elements are independent -> any batch partitioning is order-safe.
//
// PERF MODEL (measured R9/R10): time ~ L2-miss traffic / ~4.5 TB/s (L3-
// served). R10's vn FETCH=70.5MB vs 27MB unique = 3x amplification: the
// shared state working set (27MB) exceeds per-XCD L2 (4MB). FIX: batch-
// sliced dispatch — blockIdx%8 = batch-group -> XCD round-robin pins each
// 1/8 batch slice (state 2.8MB + meta 0.7MB) into its XCD's L2.

// meta bits: [2:0]=amin, [9:3]=nm (neg mask), [10]=stot (parity)

// ---------------------------------------------------------------------
// prep: lch[(2Z+n)*128 + b] = -clip(llr[b*N_TX + n])   (tiled transpose)
// ---------------------------------------------------------------------
__global__ void prep_kernel(const float* __restrict__ llr, float* __restrict__ lch) {
    __shared__ float tile[32][33];
    const int n0 = blockIdx.x * 32, b0 = blockIdx.y * 32;
    const int tx = threadIdx.x, ty = threadIdx.y;
#pragma unroll
    for (int j = 0; j < 4; ++j) {
        float v = llr[(b0 + ty + 8 * j) * N_TX + n0 + tx];
        v = fminf(fmaxf(v, -LLR_MAXF), LLR_MAXF);
        tile[ty + 8 * j][tx] = -v;          // [b_local][n_local]
    }
    __syncthreads();
#pragma unroll
    for (int j = 0; j < 4; ++j) {
        lch[(2 * Zl + n0 + ty + 8 * j) * BATCH + b0 + tx] = tile[tx][ty + 8 * j];
    }
}

// ---------------------------------------------------------------------
// adjacency build, deterministic ascending base-edge order.
// badj[c*BCAP + slot] = sh | (d<<10) | (r<<13)   (sh<512, d<8, r<64)
// ---------------------------------------------------------------------
__global__ void base_build_kernel(const int* __restrict__ col,
                                  int* __restrict__ bcount, int* __restrict__ badj) {
    __shared__ int sc[MBr * DEG];
    __shared__ int ssh[MBr * DEG];
    const int t = threadIdx.x;
    if (t < MBr * DEG) {
        const int v0 = col[t * Zl];         // col[be*Z] = c*Z + shift
        const int c  = v0 / Zl;
        sc[t]  = c;
        ssh[t] = v0 - c * Zl;
    }
    if (t < NBc) bcount[t] = 0;
    __syncthreads();
    if (t < MBr * DEG) {
        const int c = sc[t];
        int slot = 0;
        for (int u = 0; u < t; ++u) slot += (sc[u] == c) ? 1 : 0;
        const int r = t / DEG, d = t - r * DEG;
        if (slot < BCAP) badj[c * BCAP + slot] = ssh[t] | (d << 10) | (r << 13);
        atomicAdd(&bcount[c], 1);           // order-independent (count only)
    }
}

// ---------------------------------------------------------------------
// CN update, batch-sliced: blockIdx%8 = batch-group (quads 4g..4g+3),
// blockIdx/8 = tile of 64 check nodes. 4 lanes per node, float4 each.
// ---------------------------------------------------------------------
template <bool FIRST>
__global__ void cn_kernel(const float* __restrict__ x,
                          float* __restrict__ state_f2,
                          unsigned short* __restrict__ meta,
                          const int* __restrict__ col) {
    const int qg   = blockIdx.x & 7;          // batch group -> XCD
    const int tile = blockIdx.x >> 3;
    const int nl   = threadIdx.x >> 2;        // node within tile (0..63)
    const int ql   = threadIdx.x & 3;
    const int q    = qg * 4 + ql;             // float4 quad (0..31)
    const int cn   = tile * 64 + nl;
    const int r    = cn / Zl;
    const int i    = cn - r * Zl;
    const int ebase = r * DEG * Zl + i;

    float omin1[4], omin2[4];
    int oamin[4]; unsigned onm[4], ostot[4];
    if (!FIRST) {
        const float4 sA = ((const float4*)state_f2)[cn * 64 + 2 * q];
        const float4 sB = ((const float4*)state_f2)[cn * 64 + 2 * q + 1];
        omin1[0] = sA.x; omin2[0] = sA.y; omin1[1] = sA.z; omin2[1] = sA.w;
        omin1[2] = sB.x; omin2[2] = sB.y; omin1[3] = sB.z; omin2[3] = sB.w;
        const ushort4 mt = ((const ushort4*)meta)[cn * 32 + q];
        const unsigned m4[4] = {mt.x, mt.y, mt.z, mt.w};
#pragma unroll
        for (int c = 0; c < 4; ++c) {
            oamin[c] = m4[c] & 7u;
            onm[c]   = (m4[c] >> 3) & 0x7Fu;
            ostot[c] = (m4[c] >> 10) & 1u;
        }
    }

    float min1[4] = {1e30f, 1e30f, 1e30f, 1e30f};
    float min2[4] = {1e30f, 1e30f, 1e30f, 1e30f};
    int   amin[4] = {0, 0, 0, 0};
    unsigned nm[4] = {0u, 0u, 0u, 0u};

#pragma unroll
    for (int d = 0; d < DEG; ++d) {
        const int e = ebase + d * Zl;
        const int v = col[e];
        const float4 xv = ((const float4*)x)[v * 32 + q];
        float t[4] = {xv.x, xv.y, xv.z, xv.w};
        if (!FIRST) {
#pragma unroll
            for (int c = 0; c < 4; ++c) {
                const float omag = (d == oamin[c]) ? omin2[c] : omin1[c];
                const float mold = (ostot[c] ^ ((onm[c] >> d) & 1u)) ? -omag : omag;
                t[c] -= mold;
            }
        }
#pragma unroll
        for (int c = 0; c < 4; ++c) {
            const float mag = fabsf(t[c]);
            nm[c] |= (t[c] < 0.f ? 1u : 0u) << d;
            if (mag < min1[c]) { min2[c] = min1[c]; min1[c] = mag; amin[c] = d; }
            else if (mag < min2[c]) { min2[c] = mag; }
        }
    }

    float4 oA, oB;
    oA.x = min1[0]; oA.y = min2[0]; oA.z = min1[1]; oA.w = min2[1];
    oB.x = min1[2]; oB.y = min2[2]; oB.z = min1[3]; oB.w = min2[3];
    ((float4*)state_f2)[cn * 64 + 2 * q]     = oA;
    ((float4*)state_f2)[cn * 64 + 2 * q + 1] = oB;
    ushort4 mo;
    unsigned mv[4];
#pragma unroll
    for (int c = 0; c < 4; ++c)
        mv[c] = (unsigned)amin[c] | (nm[c] << 3) | ((unsigned)(__popc(nm[c]) & 1) << 10);
    mo.x = (unsigned short)mv[0]; mo.y = (unsigned short)mv[1];
    mo.z = (unsigned short)mv[2]; mo.w = (unsigned short)mv[3];
    ((ushort4*)meta)[cn * 32 + q] = mo;
}

// ---------------------------------------------------------------------
// VN update (LCH-FIRST), batch-sliced like cn_kernel.
// x[v] = lch[v]; then += reconstructed m_cv[e], ascending base-edge id.
// ---------------------------------------------------------------------
__global__ void vn_kernel(const float* __restrict__ lch,
                          const float* __restrict__ state_f2,
                          const unsigned short* __restrict__ meta,
                          const int* __restrict__ bcount, const int* __restrict__ badj,
                          float* __restrict__ x) {
    const int qg   = blockIdx.x & 7;
    const int tile = blockIdx.x >> 3;
    const int nl   = threadIdx.x >> 2;
    const int ql   = threadIdx.x & 3;
    const int q    = qg * 4 + ql;
    const int v    = tile * 64 + nl;
    const int c    = v / Zl;
    const int j    = v - c * Zl;
    const int cnt  = min(bcount[c], BCAP);
    const int* bp  = badj + c * BCAP;
    float4 s = ((const float4*)lch)[v * 32 + q];   // lch FIRST (scatter init)
    for (int k = 0; k < cnt; ++k) {
        const int pk = bp[k];
        const int sh = pk & 0x3FF;
        const int d  = (pk >> 10) & 7;
        const int r  = pk >> 13;
        int i = j - sh;
        if (i < 0) i += Zl;
        const int cn = r * Zl + i;
        const float4 sA = ((const float4*)state_f2)[cn * 64 + 2 * q];
        const float4 sB = ((const float4*)state_f2)[cn * 64 + 2 * q + 1];
        const ushort4 mt = ((const ushort4*)meta)[cn * 32 + q];
        const unsigned m4[4] = {mt.x, mt.y, mt.z, mt.w};
        const float mn1[4] = {sA.x, sA.z, sB.x, sB.z};
        const float mn2[4] = {sA.y, sA.w, sB.y, sB.w};
        float val[4];
#pragma unroll
        for (int cc = 0; cc < 4; ++cc) {
            const int   am  = m4[cc] & 7u;
            const unsigned nmv = (m4[cc] >> 3) & 0x7Fu;
            const unsigned st  = (m4[cc] >> 10) & 1u;
            const float mag = (d == am) ? mn2[cc] : mn1[cc];
            val[cc] = (st ^ ((nmv >> d) & 1u)) ? -mag : mag;
        }
        s.x += val[0]; s.y += val[1]; s.z += val[2]; s.w += val[3];
    }
    ((float4*)x)[v * 32 + q] = s;
}

// ---------------------------------------------------------------------
// output: out[b*K + k] = -x[k*128 + b], k < K_INFO   (tiled transpose)
// ---------------------------------------------------------------------
__global__ void out_kernel(const float* __restrict__ x, float* __restrict__ out) {
    __shared__ float tile[32][33];
    const int k0 = blockIdx.x * 32, b0 = blockIdx.y * 32;
    const int tx = threadIdx.x, ty = threadIdx.y;
#pragma unroll
    for (int j = 0; j < 4; ++j) {
        tile[ty + 8 * j][tx] = -x[(k0 + ty + 8 * j) * BATCH + b0 + tx];
    }
    __syncthreads();
#pragma unroll
    for (int j = 0; j < 4; ++j) {
        out[(b0 + ty + 8 * j) * K_INFO + k0 + tx] = tile[tx][ty + 8 * j];
    }
}

// ---------------------------------------------------------------------
extern "C" void kernel_launch(void* const* d_in, const int* in_sizes, int n_in,
                              void* d_out, int out_size, void* d_ws, size_t ws_size,
                              hipStream_t stream) {
    const float* llr = (const float*)d_in[0];
    // d_in[1] = row (unused: row index derivable from edge-id structure)
    const int* col = (const int*)d_in[2];
    float* out = (float*)d_out;

    char* ws = (char*)d_ws;
    float* lch   = (float*)ws;                                   // 13,369,344 B
    float* x     = lch + (size_t)N_LDPC * BATCH;                 // 13,369,344 B
    float* state = x + (size_t)N_LDPC * BATCH;                   // 18,087,936 B
    unsigned short* meta = (unsigned short*)(state + (size_t)M_CHK * BATCH * 2); // 4,521,984 B
    int* bcount = (int*)(meta + (size_t)M_CHK * BATCH);          // 68*4
    int* badj   = bcount + NBc;                                  // 68*32*4
    // total ~49.4 MB

    hipMemsetAsync(lch, 0, (size_t)(2 * Zl) * BATCH * sizeof(float), stream);
    prep_kernel<<<dim3(N_TX / 32, BATCH / 32), dim3(32, 8), 0, stream>>>(llr, lch);

    base_build_kernel<<<1, 512, 0, stream>>>(col, bcount, badj);

    // grids: (node_tiles) x 8 batch-groups; %8 -> XCD round-robin
    const int cn_grid = (M_CHK / 64) * 8;    // 276*8 = 2208
    const int vn_grid = (N_LDPC / 64) * 8;   // 408*8 = 3264

    // iteration 1: vn_sum == lch exactly (m_cv == 0)
    cn_kernel<true><<<cn_grid, 256, 0, stream>>>(lch, state, meta, col);
    vn_kernel<<<vn_grid, 256, 0, stream>>>(lch, state, meta, bcount, badj, x);

    for (int t = 1; t < NUM_ITER; ++t) {
        cn_kernel<false><<<cn_grid, 256, 0, stream>>>(x, state, meta, col);
        vn_kernel<<<vn_grid, 256, 0, stream>>>(lch, state, meta, bcount, badj, x);
    }

    out_kernel<<<dim3(K_INFO / 32, BATCH / 32), dim3(32, 8), 0, stream>>>(x, out);
}